// Round 19
// baseline (387.171 us; speedup 1.0000x reference)
//
#include <hip/hip_runtime.h>
#include <hip/hip_bf16.h>
#include <math.h>

constexpr int B_ = 4, N_ = 8192, H_ = 8;
constexpr float SQT    = 0.35355339059327373f;   // sqrt(SOFTMAX_TEMP)
constexpr float RFF_S  = 0.17677669529663687f;   // sqrt(2/64)
constexpr float RATIO  = 0.0625f;                // 256^-0.5
constexpr float SM_EPS = 1e-6f;
constexpr float NORM_EPS = 1e-6f;

constexpr int NCH = 16, CHUNK = N_ / NCH;        // pass1: 512 rows per (bh,ch), grid 32*NCH*2

// ws layout (float offsets)
constexpr int OFF_CONST = 0;
constexpr int OFF_FLAG  = 63;
constexpr int OFF_MK    = 64;
constexpr int OFF_NMASK = 96;
constexpr int OFF_KSUM  = 128;      // 32*256
constexpr int OFF_VSUM  = 8320;     // 32*64
constexpr int OFF_BMAX  = 10368;    // 1024 (32 bh * 16 ch * 2 fh)
constexpr int OFF_CTX   = 11392;    // 32*256*64 f32; finalize converts in-place to bf16 ctxT[bh][64][256]
constexpr int OFF_OWB   = 535680;   // 64*512 bf16 out_w (16384 float-slots)
constexpr int ZERO_BEG  = OFF_NMASK;
constexpr int ZERO_END  = OFF_CTX + 32*16384;

typedef __attribute__((ext_vector_type(8))) short short8v;
typedef __attribute__((ext_vector_type(4))) float f32x4;

__device__ __forceinline__ unsigned short f2bs(float x) {
  __hip_bfloat16 b = __float2bfloat16(x);   // HW cvt (RNE)
  return *reinterpret_cast<unsigned short*>(&b);
}
__device__ __forceinline__ float bs2f(unsigned short s) {
  union { unsigned int u; float f; } v; v.u = ((unsigned int)s) << 16;
  return v.f;
}

__global__ __launch_bounds__(256)
void k_consts(const float* __restrict__ wrpe, const float* __restrict__ outw,
              const unsigned int* __restrict__ maskw, float* __restrict__ W) {
  __shared__ float exs[128];
  __shared__ float qwv[8][2];
  __shared__ int f_gt1, f_oddnz, f_evennz;
  int tid = threadIdx.x;
  int nb = gridDim.x, bid = blockIdx.x;
  for (int i = bid*256 + tid; i < 32*NCH*2; i += nb*256) W[OFF_BMAX + i] = -INFINITY;
  unsigned short* owb = (unsigned short*)&W[OFF_OWB];
  for (int i = bid*256 + tid; i < 64*512; i += nb*256) owb[i] = f2bs(outw[i]);
  if (bid != 0) return;
  if (tid == 0) { f_gt1 = 0; f_oddnz = 0; f_evennz = 0; }
  __syncthreads();
  {
    int gt1 = 0, oddnz = 0, evennz = 0;
    for (int i = tid; i < 8192; i += 256) {
      unsigned int v = maskw[i];
      if (v > 1u) gt1 = 1;
      if (v != 0u) { if (i & 1) oddnz = 1; else evennz = 1; }
    }
    if (gt1)    atomicOr(&f_gt1, 1);
    if (oddnz)  atomicOr(&f_oddnz, 1);
    if (evennz) atomicOr(&f_evennz, 1);
  }
  if (tid < 128) {
    int h = tid >> 4, r = (tid >> 3) & 1, c = (tid >> 2) & 1, k = tid & 3;
    float s = 0.f;
    for (int d = 0; d < 64; ++d) s += wrpe[(h*64 + d)*16 + r*8 + c*4 + k];
    exs[tid] = expf(fminf(s, 50.f));
  }
  __syncthreads();
  if (tid == 0) {
    float flag = 0.f;
    if (f_gt1) flag = 1.f;
    else if (!f_oddnz && f_evennz) flag = 2.f;
    W[OFF_FLAG] = flag;
  }
  if (tid < 32) {
    int h = tid >> 2, r = (tid >> 1) & 1, c = tid & 1;
    float s = 0.f;
    for (int k = 0; k < 4; ++k) s += exs[h*16 + r*8 + c*4 + k];
    if (c == 0) W[OFF_CONST + h*8 + 3 + r] = sqrtf(s);
    else        qwv[h][r] = s;
  }
  __syncthreads();
  if (tid < 8) {
    int h = tid;
    float s0 = sqrtf(qwv[h][0]), s1 = sqrtf(qwv[h][1]);
    W[OFF_CONST + h*8 + 0] = s0;
    W[OFF_CONST + h*8 + 1] = s0;
    W[OFF_CONST + h*8 + 2] = s1;
  }
}

__device__ __forceinline__ int read_mask(const void* maskp, int mtype, size_t idx) {
  if (mtype == 1) return (int)((const unsigned char*)maskp)[idx];
  if (mtype == 2) return (int)((const long long*)maskp)[idx];
  return ((const int*)maskp)[idx];
}

// RFF: compute 8 features for this thread's sc block, return sumsq; vectorized b128 stores.
__device__ __forceinline__ float rff_store(unsigned short kcbrow[200], int sc,
                                           float px, float py, float pz,
                                           const float* omR, const float* omA,
                                           float a0, float a1) {
  float sq = 0.f;
  short8v cv8, sv8;
  if (sc < 4) {
    #pragma unroll
    for (int ii = 0; ii < 8; ++ii) {
      int idx = sc*8 + ii;
      float u = px*omR[idx] + py*omR[32+idx];
      float sn, cs; __sincosf(u, &sn, &cs);
      float cv = cs*a0, sv = sn*a0;
      cv8[ii] = f2bs(cv); sv8[ii] = f2bs(sv);
      sq += cv*cv + sv*sv;
    }
    *(short8v*)&kcbrow[64 + sc*8] = cv8;
    *(short8v*)&kcbrow[96 + sc*8] = sv8;
  } else {
    #pragma unroll
    for (int ii = 0; ii < 8; ++ii) {
      int j = (sc-4)*8 + ii;
      float u = pz*omA[j];
      float sn, cs; __sincosf(u, &sn, &cs);
      float cv = cs*a1, sv = sn*a1;
      cv8[ii] = f2bs(cv); sv8[ii] = f2bs(sv);
      sq += cv*cv + sv*sv;
    }
    *(short8v*)&kcbrow[128 + (sc-4)*8] = cv8;
    *(short8v*)&kcbrow[160 + (sc-4)*8] = sv8;
  }
  return sq;
}

// 256 threads; block = (bh, ch, fhalf): 128 features each.
__global__ __launch_bounds__(256, 3)
void k_pass1(const float* __restrict__ key, const float* __restrict__ value,
             const float* __restrict__ coords, const void* __restrict__ maskp,
             const float* __restrict__ omR_g, const float* __restrict__ omA_g,
             const float* __restrict__ proj, float* __restrict__ W) {
  int bh = blockIdx.x / (NCH*2);
  int rem = blockIdx.x % (NCH*2);
  int ch = rem >> 1, fh = rem & 1;
  int b = bh >> 3, h = bh & 7;
  int f_base = fh*128;
  int tid = threadIdx.x;
  int w = tid >> 6, lane = tid & 63, g = lane >> 4, fcol = lane & 15, g4 = g*4;

  __shared__ __align__(16) unsigned short kcb[32][200];
  __shared__ __align__(16) unsigned short vtT[64][40];   // [e][swizzled n]
  __shared__ __align__(16) unsigned short eT[128][40];
  __shared__ float red[256];
  __shared__ float diag_s[32];
  __shared__ float mtile_s[32];
  __shared__ float wred[4];
  __shared__ float omR[64], omA[32];

  if (tid < 64) omR[tid] = omR_g[tid];
  if (tid < 32) omA[tid] = omA_g[tid];
  int mtype = (int)W[OFF_FLAG];
  float s0 = W[OFF_CONST + h*8 + 0];
  float s1 = W[OFF_CONST + h*8 + 1];
  float s2 = W[OFF_CONST + h*8 + 2];
  float a0 = W[OFF_CONST + h*8 + 3] * RFF_S;
  float a1 = W[OFF_CONST + h*8 + 4] * RFF_S;

  short8v pb[2][6];
  #pragma unroll
  for (int ft = 0; ft < 2; ++ft) {
    int f = f_base + w*32 + ft*16 + fcol;
    #pragma unroll
    for (int ks = 0; ks < 6; ++ks) {
      const float* p = proj + (size_t)f*192 + ks*32 + g*8;
      float4 p0 = *(const float4*)p;
      float4 p1 = *(const float4*)(p + 4);
      short8v v;
      v[0]=f2bs(p0.x); v[1]=f2bs(p0.y); v[2]=f2bs(p0.z); v[3]=f2bs(p0.w);
      v[4]=f2bs(p1.x); v[5]=f2bs(p1.y); v[6]=f2bs(p1.z); v[7]=f2bs(p1.w);
      pb[ft][ks] = v;
    }
  }

  f32x4 ctxa[2][4];
  #pragma unroll
  for (int i = 0; i < 2; ++i)
    #pragma unroll
    for (int j = 0; j < 4; ++j) ctxa[i][j] = (f32x4){0.f,0.f,0.f,0.f};
  float ksum_p[2] = {0.f,0.f};
  float vs8[8] = {0.f,0.f,0.f,0.f,0.f,0.f,0.f,0.f};
  float maxd = -INFINITY, nm = 0.f;

  int srow = tid >> 3, sc = tid & 7;
  int wgrp = srow >> 3;

  // ---- prefetch tile 0 ----
  float4 pk0, pk1, pv0, pv1;
  float pcx, pcy, pcz, pmv;
  {
    size_t nidx = (size_t)b*N_ + ch*CHUNK + srow;
    const float* kp = key + nidx*512 + h*64 + sc*8;
    const float* vp = value + nidx*512 + h*64 + sc*8;
    pk0 = *(const float4*)kp; pk1 = *(const float4*)(kp+4);
    pv0 = *(const float4*)vp; pv1 = *(const float4*)(vp+4);
    const float* cp = coords + nidx*3;
    pcx = cp[0]; pcy = cp[1]; pcz = cp[2];
    pmv = (read_mask(maskp, mtype, nidx) != 0) ? 1.f : 0.f;
  }

  for (int t = 0; t < CHUNK/32; ++t) {
    __syncthreads();
    {
      float kk[8] = {pk0.x*SQT,pk0.y*SQT,pk0.z*SQT,pk0.w*SQT,pk1.x*SQT,pk1.y*SQT,pk1.z*SQT,pk1.w*SQT};
      float sq = 0.f;
      short8v kv;
      #pragma unroll
      for (int i = 0; i < 8; ++i) { sq += kk[i]*kk[i]; kv[i] = f2bs(kk[i]); }
      *(short8v*)&kcb[srow][sc*8] = kv;
      float vv[8] = {pv0.x,pv0.y,pv0.z,pv0.w,pv1.x,pv1.y,pv1.z,pv1.w};
      {
        int col = ((wgrp ^ (sc & 3)) << 3) | (srow & 7);
        #pragma unroll
        for (int i = 0; i < 8; ++i) vtT[sc*8 + i][col] = f2bs(vv[i]);
      }
      if (fh == 0 && pmv != 0.f) {
        #pragma unroll
        for (int i = 0; i < 8; ++i) vs8[i] += vv[i];
      }
      sq += rff_store(kcb[srow], sc, pcx*s0, pcy*s1, pcz*s2, omR, omA, a0, a1);
      red[tid] = sq;
      if (sc == 0) mtile_s[srow] = pmv;
    }
    if (t+1 < CHUNK/32) {
      size_t nidx = (size_t)b*N_ + ch*CHUNK + (t+1)*32 + srow;
      const float* kp = key + nidx*512 + h*64 + sc*8;
      const float* vp = value + nidx*512 + h*64 + sc*8;
      pk0 = *(const float4*)kp; pk1 = *(const float4*)(kp+4);
      pv0 = *(const float4*)vp; pv1 = *(const float4*)(vp+4);
      const float* cp = coords + nidx*3;
      pcx = cp[0]; pcy = cp[1]; pcz = cp[2];
      pmv = (read_mask(maskp, mtype, nidx) != 0) ? 1.f : 0.f;
    }
    __syncthreads();
    if (tid < 32) {
      float s = 0.f;
      #pragma unroll
      for (int c = 0; c < 8; ++c) s += red[tid*8 + c];
      diag_s[tid] = 0.5f*s;
    }
    f32x4 d[2][2];
    #pragma unroll
    for (int hh = 0; hh < 2; ++hh)
      #pragma unroll
      for (int ft = 0; ft < 2; ++ft) d[hh][ft] = (f32x4){0,0,0,0};
    #pragma unroll
    for (int ks = 0; ks < 6; ++ks) {
      short8v alo = *(const short8v*)&kcb[fcol][ks*32 + g*8];
      short8v ahi = *(const short8v*)&kcb[16 + fcol][ks*32 + g*8];
      #pragma unroll
      for (int ft = 0; ft < 2; ++ft) {
        d[0][ft] = __builtin_amdgcn_mfma_f32_16x16x32_bf16(alo, pb[ft][ks], d[0][ft], 0, 0, 0);
        d[1][ft] = __builtin_amdgcn_mfma_f32_16x16x32_bf16(ahi, pb[ft][ks], d[1][ft], 0, 0, 0);
      }
    }
    __syncthreads();
    if (tid < 32) nm += mtile_s[tid];
    #pragma unroll
    for (int ft = 0; ft < 2; ++ft) {
      int fl = w*32 + ft*16 + fcol;
      #pragma unroll
      for (int hh = 0; hh < 2; ++hh) {
        unsigned short us[4];
        #pragma unroll
        for (int j = 0; j < 4; ++j) {
          int n = hh*16 + g4 + j;
          float x = d[hh][ft][j];
          maxd = fmaxf(maxd, x);
          float E = (mtile_s[n] != 0.f) ? __expf(x - diag_s[n]) : 0.f;
          ksum_p[ft] += E;
          us[j] = f2bs(E);
        }
        *(unsigned int*)&eT[fl][hh*16 + g4]     = (unsigned int)us[0] | ((unsigned int)us[1] << 16);
        *(unsigned int*)&eT[fl][hh*16 + g4 + 2] = (unsigned int)us[2] | ((unsigned int)us[3] << 16);
      }
    }
    __syncthreads();
    {
      short8v av[2];
      #pragma unroll
      for (int ft = 0; ft < 2; ++ft)
        av[ft] = *(const short8v*)&eT[w*32 + ft*16 + fcol][g*8];
      #pragma unroll
      for (int et = 0; et < 4; ++et) {
        int e = et*16 + fcol;
        int gr = g ^ ((e >> 3) & 3);
        short8v bv = *(const short8v*)&vtT[e][gr*8];
        #pragma unroll
        for (int ft = 0; ft < 2; ++ft)
          ctxa[ft][et] = __builtin_amdgcn_mfma_f32_16x16x32_bf16(av[ft], bv, ctxa[ft][et], 0, 0, 0);
      }
    }
  }

  #pragma unroll
  for (int ft = 0; ft < 2; ++ft) {
    float k0 = ksum_p[ft];
    k0 += __shfl_xor(k0, 16);
    k0 += __shfl_xor(k0, 32);
    if (g == 0)
      atomicAdd(&W[OFF_KSUM + bh*256 + f_base + w*32 + ft*16 + fcol], k0);
  }
  #pragma unroll
  for (int ft = 0; ft < 2; ++ft)
    #pragma unroll
    for (int et = 0; et < 4; ++et)
      #pragma unroll
      for (int j = 0; j < 4; ++j) {
        int f = f_base + w*32 + ft*16 + g4 + j;
        int e = et*16 + fcol;
        atomicAdd(&W[OFF_CTX + (size_t)bh*16384 + f*64 + e], ctxa[ft][et][j]);
      }
  if (fh == 0) {
    #pragma unroll
    for (int m = 8; m <= 32; m <<= 1)
      #pragma unroll
      for (int i = 0; i < 8; ++i) vs8[i] += __shfl_xor(vs8[i], m);
    __syncthreads();
    if (lane < 8) {
      #pragma unroll
      for (int i = 0; i < 8; ++i) red[w*64 + lane*8 + i] = vs8[i];
    }
    __syncthreads();
    if (tid < 64) {
      float s = red[tid] + red[64+tid] + red[128+tid] + red[192+tid];
      atomicAdd(&W[OFF_VSUM + bh*64 + tid], s);
    }
    if (tid < 32) {
      float nn = nm;
      nn += __shfl_xor(nn, 1); nn += __shfl_xor(nn, 2);
      nn += __shfl_xor(nn, 4); nn += __shfl_xor(nn, 8);
      nn += __shfl_xor(nn, 16);
      if (tid == 0) atomicAdd(&W[OFF_NMASK + bh], nn);
    }
  }
  #pragma unroll
  for (int m = 1; m <= 32; m <<= 1) maxd = fmaxf(maxd, __shfl_xor(maxd, m));
  if (lane == 0) wred[w] = maxd;
  __syncthreads();
  if (tid == 0) {
    float m = fmaxf(fmaxf(wred[0], wred[1]), fmaxf(wred[2], wred[3]));
    W[OFF_BMAX + blockIdx.x] = m;
  }
}

// finalize: per-bh global max, scale ksum/ctx, convert ctx to bf16 ctxT
__global__ __launch_bounds__(256)
void k_finalize(float* __restrict__ W) {
  __shared__ float buf[16384];
  __shared__ float mk_s;
  int bh = blockIdx.x;
  int tid = threadIdx.x;
  if (tid < 32) {
    float m = W[OFF_BMAX + bh*(NCH*2) + tid];
    #pragma unroll
    for (int s = 1; s < 32; s <<= 1) m = fmaxf(m, __shfl_xor(m, s));
    if (tid == 0) { mk_s = m; W[OFF_MK + bh] = m; }
  }
  __syncthreads();
  float emk  = RATIO * __expf(-mk_s);
  float epsr = RATIO * SM_EPS;
  float nm = W[OFF_NMASK + bh];
  W[OFF_KSUM + bh*256 + tid] = emk*W[OFF_KSUM + bh*256 + tid] + epsr*nm;
  float* ctx = &W[OFF_CTX + (size_t)bh*16384];
  const float* vsum = &W[OFF_VSUM + bh*64];
  for (int i = tid; i < 16384; i += 256) {
    int e = i & 63;
    buf[i] = emk*ctx[i] + epsr*vsum[e];
  }
  __syncthreads();
  unsigned short* ct = (unsigned short*)ctx;
  for (int i = tid; i < 16384; i += 256) {
    int e = i >> 8, f = i & 255;
    ct[i] = f2bs(buf[f*64 + e]);
  }
}

__global__ __launch_bounds__(256, 3)
void k_pass2(const float* __restrict__ query, const float* __restrict__ coords,
             const float* __restrict__ omR_g, const float* __restrict__ omA_g,
             const float* __restrict__ proj, const float* __restrict__ outb,
             float* __restrict__ W, float* __restrict__ out) {
  int b  = blockIdx.x >> 8;
  int n0 = (blockIdx.x & 255) * 32;
  int tid = threadIdx.x;
  int w = tid >> 6, lane = tid & 63, g = lane >> 4, fcol = lane & 15, g4 = g*4;

  __shared__ __align__(16) unsigned short kcb[32][200];
  __shared__ __align__(16) unsigned short qpE[32][280];
  __shared__ __align__(16) unsigned short attnb[32][72];
  __shared__ float red[32][8];
  __shared__ float diag_s[32];
  __shared__ float mredw[4][32];
  __shared__ float red2[4][32];
  __shared__ float mq[32];
  __shared__ float dnm[32];
  __shared__ float ksl[256];
  __shared__ float omR[64], omA[32];

  if (tid < 64) omR[tid] = omR_g[tid];
  if (tid < 32) omA[tid] = omA_g[tid];

  short8v pb[4][6];
  #pragma unroll
  for (int ft = 0; ft < 4; ++ft) {
    int f = w*64 + ft*16 + fcol;
    #pragma unroll
    for (int ks = 0; ks < 6; ++ks) {
      const float* p = proj + (size_t)f*192 + ks*32 + g*8;
      float4 p0 = *(const float4*)p;
      float4 p1 = *(const float4*)(p + 4);
      short8v v;
      v[0]=f2bs(p0.x); v[1]=f2bs(p0.y); v[2]=f2bs(p0.z); v[3]=f2bs(p0.w);
      v[4]=f2bs(p1.x); v[5]=f2bs(p1.y); v[6]=f2bs(p1.z); v[7]=f2bs(p1.w);
      pb[ft][ks] = v;
    }
  }

  const unsigned short* owb = (const unsigned short*)&W[OFF_OWB];
  int srow = tid >> 3, sc = tid & 7;
  f32x4 oacc[2];
  oacc[0] = (f32x4){0,0,0,0}; oacc[1] = (f32x4){0,0,0,0};

  float cx, cy, cz;
  float4 pq0, pq1;
  {
    size_t nidx = (size_t)b*N_ + n0 + srow;
    const float* cp = coords + nidx*3;
    cx = cp[0]; cy = cp[1]; cz = cp[2];
    const float* qp_ = query + nidx*512 + sc*8;
    pq0 = *(const float4*)qp_; pq1 = *(const float4*)(qp_+4);
  }

  for (int h = 0; h < 8; ++h) {
    int bh = b*8 + h;
    float s0 = W[OFF_CONST + h*8 + 0];
    float s1 = W[OFF_CONST + h*8 + 1];
    float s2 = W[OFF_CONST + h*8 + 2];
    float a0 = W[OFF_CONST + h*8 + 3] * RFF_S;
    float a1 = W[OFF_CONST + h*8 + 4] * RFF_S;
    __syncthreads();
    ksl[tid] = W[OFF_KSUM + bh*256 + tid];
    {
      float kk[8] = {pq0.x*SQT,pq0.y*SQT,pq0.z*SQT,pq0.w*SQT,pq1.x*SQT,pq1.y*SQT,pq1.z*SQT,pq1.w*SQT};
      float sq = 0.f;
      short8v kv;
      #pragma unroll
      for (int i = 0; i < 8; ++i) { sq += kk[i]*kk[i]; kv[i] = f2bs(kk[i]); }
      *(short8v*)&kcb[srow][sc*8] = kv;
      sq += rff_store(kcb[srow], sc, cx*s0, cy*s1, cz*s2, omR, omA, a0, a1);
      red[srow][sc] = sq;
    }
    if (h+1 < 8) {
      const float* qp_ = query + ((size_t)b*N_ + n0 + srow)*512 + (h+1)*64 + sc*8;
      pq0 = *(const float4*)qp_; pq1 = *(const float4*)(qp_+4);
    }
    __syncthreads();
    if (lane < 8) {
      int row = w*8 + lane;
      float s = 0.f;
      #pragma unroll
      for (int c = 0; c < 8; ++c) s += red[row][c];
      diag_s[row] = 0.5f*s;
    }
    f32x4 dlo[4], dhi[4];
    #pragma unroll
    for (int ft = 0; ft < 4; ++ft) { dlo[ft] = (f32x4){0,0,0,0}; dhi[ft] = (f32x4){0,0,0,0}; }
    #pragma unroll
    for (int ks = 0; ks < 6; ++ks) {
      short8v alo = *(const short8v*)&kcb[fcol][ks*32 + g*8];
      short8v ahi = *(const short8v*)&kcb[16+fcol][ks*32 + g*8];
      #pragma unroll
      for (int ft = 0; ft < 4; ++ft) {
        dlo[ft] = __builtin_amdgcn_mfma_f32_16x16x32_bf16(alo, pb[ft][ks], dlo[ft], 0, 0, 0);
        dhi[ft] = __builtin_amdgcn_mfma_f32_16x16x32_bf16(ahi, pb[ft][ks], dhi[ft], 0, 0, 0);
      }
    }
    {
      float ml[4], mh[4];
      #pragma unroll
      for (int j = 0; j < 4; ++j) {
        ml[j] = fmaxf(fmaxf(dlo[0][j], dlo[1][j]), fmaxf(dlo[2][j], dlo[3][j]));
        mh[j] = fmaxf(fmaxf(dhi[0][j], dhi[1][j]), fmaxf(dhi[2][j], dhi[3][j]));
      }
      #pragma unroll
      for (int m = 1; m <= 8; m <<= 1) {
        #pragma unroll
        for (int j = 0; j < 4; ++j) {
          ml[j] = fmaxf(ml[j], __shfl_xor(ml[j], m));
          mh[j] = fmaxf(mh[j], __shfl_xor(mh[j], m));
        }
      }
      if (fcol == 0) {
        #pragma unroll
        for (int j = 0; j < 4; ++j) {
          mredw[w][g4+j] = ml[j];
          mredw[w][16+g4+j] = mh[j];
        }
      }
    }
    __syncthreads();
    if (tid < 32)
      mq[tid] = fmaxf(fmaxf(mredw[0][tid], mredw[1][tid]), fmaxf(mredw[2][tid], mredw[3][tid]));
    __syncthreads();
    {
      float dp[8] = {0,0,0,0,0,0,0,0};
      #pragma unroll
      for (int ft = 0; ft < 4; ++ft) {
        int f = w*64 + ft*16 + fcol;
        float kf = ksl[f];
        #pragma unroll
        for (int j = 0; j < 4; ++j) {
          int n = g4 + j;
          float Ex = RATIO * (__expf(dlo[ft][j] - diag_s[n] - mq[n]) + SM_EPS);
          dp[j] += Ex * kf;
          qpE[n][f] = f2bs(Ex);
          int n2 = 16 + g4 + j;
          float Ex2 = RATIO * (__expf(dhi[ft][j] - diag_s[n2] - mq[n2]) + SM_EPS);
          dp[4+j] += Ex2 * kf;
          qpE[n2][f] = f2bs(Ex2);
        }
      }
      #pragma unroll
      for (int m = 1; m <= 8; m <<= 1)
        #pragma unroll
        for (int s = 0; s < 8; ++s) dp[s] += __shfl_xor(dp[s], m);
      if (fcol == 0) {
        #pragma unroll
        for (int j = 0; j < 4; ++j) {
          red2[w][g4+j] = dp[j];
          red2[w][16+g4+j] = dp[4+j];
        }
      }
    }
    __syncthreads();
    if (tid < 32)
      dnm[tid] = 1.f / (red2[0][tid] + red2[1][tid] + red2[2][tid] + red2[3][tid] + NORM_EPS);
    __syncthreads();
    {
      const unsigned short* ct = (const unsigned short*)&W[OFF_CTX + (size_t)bh*16384];
      int e = w*16 + fcol;
      f32x4 pa[2];
      pa[0] = (f32x4){0,0,0,0}; pa[1] = (f32x4){0,0,0,0};
      #pragma unroll
      for (int ks = 0; ks < 8; ++ks) {
        short8v bv = *(const short8v*)&ct[e*256 + ks*32 + g*8];
        short8v a0v = *(const short8v*)&qpE[fcol][ks*32 + g*8];
        short8v a1v = *(const short8v*)&qpE[16+fcol][ks*32 + g*8];
        pa[0] = __builtin_amdgcn_mfma_f32_16x16x32_bf16(a0v, bv, pa[0], 0, 0, 0);
        pa[1] = __builtin_amdgcn_mfma_f32_16x16x32_bf16(a1v, bv, pa[1], 0, 0, 0);
      }
      #pragma unroll
      for (int rt = 0; rt < 2; ++rt)
        #pragma unroll
        for (int j = 0; j < 4; ++j) {
          int n = rt*16 + g4 + j;
          attnb[n][e] = f2bs(pa[rt][j] * dnm[n]);
        }
    }
    __syncthreads();
    {
      #pragma unroll
      for (int ks2 = 0; ks2 < 2; ++ks2) {
        short8v bo = *(const short8v*)&owb[(size_t)(w*16 + fcol)*512 + h*64 + ks2*32 + g*8];
        short8v aa0 = *(const short8v*)&attnb[fcol][ks2*32 + g*8];
        short8v aa1 = *(const short8v*)&attnb[16+fcol][ks2*32 + g*8];
        oacc[0] = __builtin_amdgcn_mfma_f32_16x16x32_bf16(aa0, bo, oacc[0], 0, 0, 0);
        oacc[1] = __builtin_amdgcn_mfma_f32_16x16x32_bf16(aa1, bo, oacc[1], 0, 0, 0);
      }
    }
  }
  {
    float bj = outb[w*16 + fcol];
    #pragma unroll
    for (int rt = 0; rt < 2; ++rt)
      #pragma unroll
      for (int j = 0; j < 4; ++j) {
        int n = n0 + rt*16 + g4 + j;
        out[((size_t)b*N_ + n)*64 + w*16 + fcol] = oacc[rt][j] + bj;
      }
  }
}

extern "C" void kernel_launch(void* const* d_in, const int* in_sizes, int n_in,
                              void* d_out, int out_size, void* d_ws, size_t ws_size,
                              hipStream_t stream) {
  const float* query  = (const float*)d_in[0];
  const float* key    = (const float*)d_in[1];
  const float* value  = (const float*)d_in[2];
  const float* coords = (const float*)d_in[3];
  const void*  mask   = d_in[4];
  const float* wrpe   = (const float*)d_in[5];
  const float* omR    = (const float*)d_in[6];
  const float* omA    = (const float*)d_in[7];
  const float* proj   = (const float*)d_in[8];
  const float* outw   = (const float*)d_in[9];
  const float* outb   = (const float*)d_in[10];
  float* W = (float*)d_ws;
  float* out = (float*)d_out;

  hipMemsetAsync(W + ZERO_BEG, 0, (size_t)(ZERO_END - ZERO_BEG)*sizeof(float), stream);
  hipLaunchKernelGGL(k_consts,   dim3(32),         dim3(256), 0, stream, wrpe, outw,
                     (const unsigned int*)mask, W);
  hipLaunchKernelGGL(k_pass1,    dim3(32*NCH*2),   dim3(256), 0, stream, key, value, coords, mask,
                     omR, omA, proj, W);
  hipLaunchKernelGGL(k_finalize, dim3(32),         dim3(256), 0, stream, W);
  hipLaunchKernelGGL(k_pass2,    dim3(1024),       dim3(256), 0, stream, query, coords, omR, omA,
                     proj, outb, W, out);
}

// Round 20
// 272.190 us; speedup vs baseline: 1.4224x; 1.4224x over previous
//
#include <hip/hip_runtime.h>
#include <hip/hip_bf16.h>
#include <math.h>

constexpr int B_ = 4, N_ = 8192, H_ = 8;
constexpr float SQT    = 0.35355339059327373f;   // sqrt(SOFTMAX_TEMP)
constexpr float RFF_S  = 0.17677669529663687f;   // sqrt(2/64)
constexpr float RATIO  = 0.0625f;                // 256^-0.5
constexpr float SM_EPS = 1e-6f;
constexpr float NORM_EPS = 1e-6f;

constexpr int NCH = 16, CHUNK = N_ / NCH;        // pass1: 512 rows per (bh,ch), grid 32*NCH*2

// ws layout (float offsets)
constexpr int OFF_CONST = 0;
constexpr int OFF_FLAG  = 63;
constexpr int OFF_MK    = 64;
constexpr int OFF_NMASK = 96;
constexpr int OFF_KSUM  = 128;      // 32*256
constexpr int OFF_VSUM  = 8320;     // 32*64
constexpr int OFF_BMAX  = 10368;    // 1024 (32 bh * 16 ch * 2 fh)
constexpr int OFF_CTX   = 11392;    // 32*256*64 f32; finalize converts in-place to bf16 ctxT[bh][64][256]
constexpr int OFF_OWB   = 535680;   // 64*512 bf16 out_w (16384 float-slots)
constexpr int ZERO_BEG  = OFF_NMASK;
constexpr int ZERO_END  = OFF_CTX + 32*16384;

typedef __attribute__((ext_vector_type(8))) short short8v;
typedef __attribute__((ext_vector_type(4))) float f32x4;

__device__ __forceinline__ unsigned short f2bs(float x) {
  __hip_bfloat16 b = __float2bfloat16(x);   // HW cvt (RNE)
  return *reinterpret_cast<unsigned short*>(&b);
}
__device__ __forceinline__ float bs2f(unsigned short s) {
  union { unsigned int u; float f; } v; v.u = ((unsigned int)s) << 16;
  return v.f;
}

__global__ __launch_bounds__(256)
void k_consts(const float* __restrict__ wrpe, const float* __restrict__ outw,
              const unsigned int* __restrict__ maskw, float* __restrict__ W) {
  __shared__ float exs[128];
  __shared__ float qwv[8][2];
  __shared__ int f_gt1, f_oddnz, f_evennz;
  int tid = threadIdx.x;
  int nb = gridDim.x, bid = blockIdx.x;
  for (int i = bid*256 + tid; i < 32*NCH*2; i += nb*256) W[OFF_BMAX + i] = -INFINITY;
  unsigned short* owb = (unsigned short*)&W[OFF_OWB];
  for (int i = bid*256 + tid; i < 64*512; i += nb*256) owb[i] = f2bs(outw[i]);
  if (bid != 0) return;
  if (tid == 0) { f_gt1 = 0; f_oddnz = 0; f_evennz = 0; }
  __syncthreads();
  {
    int gt1 = 0, oddnz = 0, evennz = 0;
    for (int i = tid; i < 8192; i += 256) {
      unsigned int v = maskw[i];
      if (v > 1u) gt1 = 1;
      if (v != 0u) { if (i & 1) oddnz = 1; else evennz = 1; }
    }
    if (gt1)    atomicOr(&f_gt1, 1);
    if (oddnz)  atomicOr(&f_oddnz, 1);
    if (evennz) atomicOr(&f_evennz, 1);
  }
  if (tid < 128) {
    int h = tid >> 4, r = (tid >> 3) & 1, c = (tid >> 2) & 1, k = tid & 3;
    float s = 0.f;
    for (int d = 0; d < 64; ++d) s += wrpe[(h*64 + d)*16 + r*8 + c*4 + k];
    exs[tid] = expf(fminf(s, 50.f));
  }
  __syncthreads();
  if (tid == 0) {
    float flag = 0.f;
    if (f_gt1) flag = 1.f;
    else if (!f_oddnz && f_evennz) flag = 2.f;
    W[OFF_FLAG] = flag;
  }
  if (tid < 32) {
    int h = tid >> 2, r = (tid >> 1) & 1, c = tid & 1;
    float s = 0.f;
    for (int k = 0; k < 4; ++k) s += exs[h*16 + r*8 + c*4 + k];
    if (c == 0) W[OFF_CONST + h*8 + 3 + r] = sqrtf(s);
    else        qwv[h][r] = s;
  }
  __syncthreads();
  if (tid < 8) {
    int h = tid;
    float s0 = sqrtf(qwv[h][0]), s1 = sqrtf(qwv[h][1]);
    W[OFF_CONST + h*8 + 0] = s0;
    W[OFF_CONST + h*8 + 1] = s0;
    W[OFF_CONST + h*8 + 2] = s1;
  }
}

__device__ __forceinline__ int read_mask(const void* maskp, int mtype, size_t idx) {
  if (mtype == 1) return (int)((const unsigned char*)maskp)[idx];
  if (mtype == 2) return (int)((const long long*)maskp)[idx];
  return ((const int*)maskp)[idx];
}

// RFF: compute 8 features for this thread's sc block, return sumsq; vectorized b128 stores.
__device__ __forceinline__ float rff_store(unsigned short kcbrow[200], int sc,
                                           float px, float py, float pz,
                                           const float* omR, const float* omA,
                                           float a0, float a1) {
  float sq = 0.f;
  short8v cv8, sv8;
  if (sc < 4) {
    #pragma unroll
    for (int ii = 0; ii < 8; ++ii) {
      int idx = sc*8 + ii;
      float u = px*omR[idx] + py*omR[32+idx];
      float sn, cs; __sincosf(u, &sn, &cs);
      float cv = cs*a0, sv = sn*a0;
      cv8[ii] = f2bs(cv); sv8[ii] = f2bs(sv);
      sq += cv*cv + sv*sv;
    }
    *(short8v*)&kcbrow[64 + sc*8] = cv8;
    *(short8v*)&kcbrow[96 + sc*8] = sv8;
  } else {
    #pragma unroll
    for (int ii = 0; ii < 8; ++ii) {
      int j = (sc-4)*8 + ii;
      float u = pz*omA[j];
      float sn, cs; __sincosf(u, &sn, &cs);
      float cv = cs*a1, sv = sn*a1;
      cv8[ii] = f2bs(cv); sv8[ii] = f2bs(sv);
      sq += cv*cv + sv*sv;
    }
    *(short8v*)&kcbrow[128 + (sc-4)*8] = cv8;
    *(short8v*)&kcbrow[160 + (sc-4)*8] = sv8;
  }
  return sq;
}

// 256 threads; block = (bh, ch, fhalf): 128 features each.
__global__ __launch_bounds__(256, 2)
void k_pass1(const float* __restrict__ key, const float* __restrict__ value,
             const float* __restrict__ coords, const void* __restrict__ maskp,
             const float* __restrict__ omR_g, const float* __restrict__ omA_g,
             const float* __restrict__ proj, float* __restrict__ W) {
  int bh = blockIdx.x / (NCH*2);
  int rem = blockIdx.x % (NCH*2);
  int ch = rem >> 1, fh = rem & 1;
  int b = bh >> 3, h = bh & 7;
  int f_base = fh*128;
  int tid = threadIdx.x;
  int w = tid >> 6, lane = tid & 63, g = lane >> 4, fcol = lane & 15, g4 = g*4;

  __shared__ __align__(16) unsigned short kcb[32][200];
  __shared__ __align__(16) unsigned short vtT[64][40];   // [e][swizzled n]
  __shared__ __align__(16) unsigned short eT[128][40];
  __shared__ float red[256];
  __shared__ float diag_s[32];
  __shared__ float mtile_s[32];
  __shared__ float wred[4];
  __shared__ float omR[64], omA[32];

  if (tid < 64) omR[tid] = omR_g[tid];
  if (tid < 32) omA[tid] = omA_g[tid];
  int mtype = (int)W[OFF_FLAG];
  float s0 = W[OFF_CONST + h*8 + 0];
  float s1 = W[OFF_CONST + h*8 + 1];
  float s2 = W[OFF_CONST + h*8 + 2];
  float a0 = W[OFF_CONST + h*8 + 3] * RFF_S;
  float a1 = W[OFF_CONST + h*8 + 4] * RFF_S;

  short8v pb[2][6];
  #pragma unroll
  for (int ft = 0; ft < 2; ++ft) {
    int f = f_base + w*32 + ft*16 + fcol;
    #pragma unroll
    for (int ks = 0; ks < 6; ++ks) {
      const float* p = proj + (size_t)f*192 + ks*32 + g*8;
      float4 p0 = *(const float4*)p;
      float4 p1 = *(const float4*)(p + 4);
      short8v v;
      v[0]=f2bs(p0.x); v[1]=f2bs(p0.y); v[2]=f2bs(p0.z); v[3]=f2bs(p0.w);
      v[4]=f2bs(p1.x); v[5]=f2bs(p1.y); v[6]=f2bs(p1.z); v[7]=f2bs(p1.w);
      pb[ft][ks] = v;
    }
  }

  f32x4 ctxa[2][4];
  #pragma unroll
  for (int i = 0; i < 2; ++i)
    #pragma unroll
    for (int j = 0; j < 4; ++j) ctxa[i][j] = (f32x4){0.f,0.f,0.f,0.f};
  float ksum_p[2] = {0.f,0.f};
  float vs8[8] = {0.f,0.f,0.f,0.f,0.f,0.f,0.f,0.f};
  float maxd = -INFINITY, nm = 0.f;

  int srow = tid >> 3, sc = tid & 7;
  int wgrp = srow >> 3;

  // ---- prefetch tile 0 ----
  float4 pk0, pk1, pv0, pv1;
  float pcx, pcy, pcz, pmv;
  {
    size_t nidx = (size_t)b*N_ + ch*CHUNK + srow;
    const float* kp = key + nidx*512 + h*64 + sc*8;
    const float* vp = value + nidx*512 + h*64 + sc*8;
    pk0 = *(const float4*)kp; pk1 = *(const float4*)(kp+4);
    pv0 = *(const float4*)vp; pv1 = *(const float4*)(vp+4);
    const float* cp = coords + nidx*3;
    pcx = cp[0]; pcy = cp[1]; pcz = cp[2];
    pmv = (read_mask(maskp, mtype, nidx) != 0) ? 1.f : 0.f;
  }

  for (int t = 0; t < CHUNK/32; ++t) {
    __syncthreads();
    {
      float kk[8] = {pk0.x*SQT,pk0.y*SQT,pk0.z*SQT,pk0.w*SQT,pk1.x*SQT,pk1.y*SQT,pk1.z*SQT,pk1.w*SQT};
      float sq = 0.f;
      short8v kv;
      #pragma unroll
      for (int i = 0; i < 8; ++i) { sq += kk[i]*kk[i]; kv[i] = f2bs(kk[i]); }
      *(short8v*)&kcb[srow][sc*8] = kv;
      float vv[8] = {pv0.x,pv0.y,pv0.z,pv0.w,pv1.x,pv1.y,pv1.z,pv1.w};
      {
        int col = ((wgrp ^ (sc & 3)) << 3) | (srow & 7);
        #pragma unroll
        for (int i = 0; i < 8; ++i) vtT[sc*8 + i][col] = f2bs(vv[i]);
      }
      if (fh == 0 && pmv != 0.f) {
        #pragma unroll
        for (int i = 0; i < 8; ++i) vs8[i] += vv[i];
      }
      sq += rff_store(kcb[srow], sc, pcx*s0, pcy*s1, pcz*s2, omR, omA, a0, a1);
      red[tid] = sq;
      if (sc == 0) mtile_s[srow] = pmv;
    }
    if (t+1 < CHUNK/32) {
      size_t nidx = (size_t)b*N_ + ch*CHUNK + (t+1)*32 + srow;
      const float* kp = key + nidx*512 + h*64 + sc*8;
      const float* vp = value + nidx*512 + h*64 + sc*8;
      pk0 = *(const float4*)kp; pk1 = *(const float4*)(kp+4);
      pv0 = *(const float4*)vp; pv1 = *(const float4*)(vp+4);
      const float* cp = coords + nidx*3;
      pcx = cp[0]; pcy = cp[1]; pcz = cp[2];
      pmv = (read_mask(maskp, mtype, nidx) != 0) ? 1.f : 0.f;
    }
    __syncthreads();
    if (tid < 32) {
      float s = 0.f;
      #pragma unroll
      for (int c = 0; c < 8; ++c) s += red[tid*8 + c];
      diag_s[tid] = 0.5f*s;
    }
    f32x4 d[2][2];
    #pragma unroll
    for (int hh = 0; hh < 2; ++hh)
      #pragma unroll
      for (int ft = 0; ft < 2; ++ft) d[hh][ft] = (f32x4){0,0,0,0};
    #pragma unroll
    for (int ks = 0; ks < 6; ++ks) {
      short8v alo = *(const short8v*)&kcb[fcol][ks*32 + g*8];
      short8v ahi = *(const short8v*)&kcb[16 + fcol][ks*32 + g*8];
      #pragma unroll
      for (int ft = 0; ft < 2; ++ft) {
        d[0][ft] = __builtin_amdgcn_mfma_f32_16x16x32_bf16(alo, pb[ft][ks], d[0][ft], 0, 0, 0);
        d[1][ft] = __builtin_amdgcn_mfma_f32_16x16x32_bf16(ahi, pb[ft][ks], d[1][ft], 0, 0, 0);
      }
    }
    __syncthreads();
    if (tid < 32) nm += mtile_s[tid];
    #pragma unroll
    for (int ft = 0; ft < 2; ++ft) {
      int fl = w*32 + ft*16 + fcol;
      #pragma unroll
      for (int hh = 0; hh < 2; ++hh) {
        unsigned short us[4];
        #pragma unroll
        for (int j = 0; j < 4; ++j) {
          int n = hh*16 + g4 + j;
          float x = d[hh][ft][j];
          maxd = fmaxf(maxd, x);
          float E = (mtile_s[n] != 0.f) ? __expf(x - diag_s[n]) : 0.f;
          ksum_p[ft] += E;
          us[j] = f2bs(E);
        }
        *(unsigned int*)&eT[fl][hh*16 + g4]     = (unsigned int)us[0] | ((unsigned int)us[1] << 16);
        *(unsigned int*)&eT[fl][hh*16 + g4 + 2] = (unsigned int)us[2] | ((unsigned int)us[3] << 16);
      }
    }
    __syncthreads();
    {
      short8v av[2];
      #pragma unroll
      for (int ft = 0; ft < 2; ++ft)
        av[ft] = *(const short8v*)&eT[w*32 + ft*16 + fcol][g*8];
      #pragma unroll
      for (int et = 0; et < 4; ++et) {
        int e = et*16 + fcol;
        int gr = g ^ ((e >> 3) & 3);
        short8v bv = *(const short8v*)&vtT[e][gr*8];
        #pragma unroll
        for (int ft = 0; ft < 2; ++ft)
          ctxa[ft][et] = __builtin_amdgcn_mfma_f32_16x16x32_bf16(av[ft], bv, ctxa[ft][et], 0, 0, 0);
      }
    }
  }

  #pragma unroll
  for (int ft = 0; ft < 2; ++ft) {
    float k0 = ksum_p[ft];
    k0 += __shfl_xor(k0, 16);
    k0 += __shfl_xor(k0, 32);
    if (g == 0)
      atomicAdd(&W[OFF_KSUM + bh*256 + f_base + w*32 + ft*16 + fcol], k0);
  }
  #pragma unroll
  for (int ft = 0; ft < 2; ++ft)
    #pragma unroll
    for (int et = 0; et < 4; ++et)
      #pragma unroll
      for (int j = 0; j < 4; ++j) {
        int f = f_base + w*32 + ft*16 + g4 + j;
        int e = et*16 + fcol;
        atomicAdd(&W[OFF_CTX + (size_t)bh*16384 + f*64 + e], ctxa[ft][et][j]);
      }
  if (fh == 0) {
    #pragma unroll
    for (int m = 8; m <= 32; m <<= 1)
      #pragma unroll
      for (int i = 0; i < 8; ++i) vs8[i] += __shfl_xor(vs8[i], m);
    __syncthreads();
    if (lane < 8) {
      #pragma unroll
      for (int i = 0; i < 8; ++i) red[w*64 + lane*8 + i] = vs8[i];
    }
    __syncthreads();
    if (tid < 64) {
      float s = red[tid] + red[64+tid] + red[128+tid] + red[192+tid];
      atomicAdd(&W[OFF_VSUM + bh*64 + tid], s);
    }
    if (tid < 32) {
      float nn = nm;
      nn += __shfl_xor(nn, 1); nn += __shfl_xor(nn, 2);
      nn += __shfl_xor(nn, 4); nn += __shfl_xor(nn, 8);
      nn += __shfl_xor(nn, 16);
      if (tid == 0) atomicAdd(&W[OFF_NMASK + bh], nn);
    }
  }
  #pragma unroll
  for (int m = 1; m <= 32; m <<= 1) maxd = fmaxf(maxd, __shfl_xor(maxd, m));
  if (lane == 0) wred[w] = maxd;
  __syncthreads();
  if (tid == 0) {
    float m = fmaxf(fmaxf(wred[0], wred[1]), fmaxf(wred[2], wred[3]));
    W[OFF_BMAX + blockIdx.x] = m;
  }
}

// finalize: per-bh global max, scale ksum/ctx, convert ctx to bf16 ctxT
__global__ __launch_bounds__(256)
void k_finalize(float* __restrict__ W) {
  __shared__ float buf[16384];
  __shared__ float mk_s;
  int bh = blockIdx.x;
  int tid = threadIdx.x;
  if (tid < 32) {
    float m = W[OFF_BMAX + bh*(NCH*2) + tid];
    #pragma unroll
    for (int s = 1; s < 32; s <<= 1) m = fmaxf(m, __shfl_xor(m, s));
    if (tid == 0) { mk_s = m; W[OFF_MK + bh] = m; }
  }
  __syncthreads();
  float emk  = RATIO * __expf(-mk_s);
  float epsr = RATIO * SM_EPS;
  float nm = W[OFF_NMASK + bh];
  W[OFF_KSUM + bh*256 + tid] = emk*W[OFF_KSUM + bh*256 + tid] + epsr*nm;
  float* ctx = &W[OFF_CTX + (size_t)bh*16384];
  const float* vsum = &W[OFF_VSUM + bh*64];
  for (int i = tid; i < 16384; i += 256) {
    int e = i & 63;
    buf[i] = emk*ctx[i] + epsr*vsum[e];
  }
  __syncthreads();
  unsigned short* ct = (unsigned short*)ctx;
  for (int i = tid; i < 16384; i += 256) {
    int e = i >> 8, f = i & 255;
    ct[i] = f2bs(buf[f*64 + e]);
  }
}

__global__ __launch_bounds__(256, 2)
void k_pass2(const float* __restrict__ query, const float* __restrict__ coords,
             const float* __restrict__ omR_g, const float* __restrict__ omA_g,
             const float* __restrict__ proj, const float* __restrict__ outb,
             float* __restrict__ W, float* __restrict__ out) {
  int b  = blockIdx.x >> 8;
  int n0 = (blockIdx.x & 255) * 32;
  int tid = threadIdx.x;
  int w = tid >> 6, lane = tid & 63, g = lane >> 4, fcol = lane & 15, g4 = g*4;

  __shared__ __align__(16) unsigned short kcb[32][200];
  __shared__ __align__(16) unsigned short qpE[32][280];
  __shared__ __align__(16) unsigned short attnb[32][72];
  __shared__ float red[32][8];
  __shared__ float diag_s[32];
  __shared__ float mredw[4][32];
  __shared__ float red2[4][32];
  __shared__ float mq[32];
  __shared__ float dnm[32];
  __shared__ float ksl[256];
  __shared__ float omR[64], omA[32];

  if (tid < 64) omR[tid] = omR_g[tid];
  if (tid < 32) omA[tid] = omA_g[tid];

  short8v pb[4][6];
  #pragma unroll
  for (int ft = 0; ft < 4; ++ft) {
    int f = w*64 + ft*16 + fcol;
    #pragma unroll
    for (int ks = 0; ks < 6; ++ks) {
      const float* p = proj + (size_t)f*192 + ks*32 + g*8;
      float4 p0 = *(const float4*)p;
      float4 p1 = *(const float4*)(p + 4);
      short8v v;
      v[0]=f2bs(p0.x); v[1]=f2bs(p0.y); v[2]=f2bs(p0.z); v[3]=f2bs(p0.w);
      v[4]=f2bs(p1.x); v[5]=f2bs(p1.y); v[6]=f2bs(p1.z); v[7]=f2bs(p1.w);
      pb[ft][ks] = v;
    }
  }

  const unsigned short* owb = (const unsigned short*)&W[OFF_OWB];
  int srow = tid >> 3, sc = tid & 7;
  f32x4 oacc[2];
  oacc[0] = (f32x4){0,0,0,0}; oacc[1] = (f32x4){0,0,0,0};

  float cx, cy, cz;
  float4 pq0, pq1;
  {
    size_t nidx = (size_t)b*N_ + n0 + srow;
    const float* cp = coords + nidx*3;
    cx = cp[0]; cy = cp[1]; cz = cp[2];
    const float* qp_ = query + nidx*512 + sc*8;
    pq0 = *(const float4*)qp_; pq1 = *(const float4*)(qp_+4);
  }

  for (int h = 0; h < 8; ++h) {
    int bh = b*8 + h;
    float s0 = W[OFF_CONST + h*8 + 0];
    float s1 = W[OFF_CONST + h*8 + 1];
    float s2 = W[OFF_CONST + h*8 + 2];
    float a0 = W[OFF_CONST + h*8 + 3] * RFF_S;
    float a1 = W[OFF_CONST + h*8 + 4] * RFF_S;
    __syncthreads();
    ksl[tid] = W[OFF_KSUM + bh*256 + tid];
    {
      float kk[8] = {pq0.x*SQT,pq0.y*SQT,pq0.z*SQT,pq0.w*SQT,pq1.x*SQT,pq1.y*SQT,pq1.z*SQT,pq1.w*SQT};
      float sq = 0.f;
      short8v kv;
      #pragma unroll
      for (int i = 0; i < 8; ++i) { sq += kk[i]*kk[i]; kv[i] = f2bs(kk[i]); }
      *(short8v*)&kcb[srow][sc*8] = kv;
      sq += rff_store(kcb[srow], sc, cx*s0, cy*s1, cz*s2, omR, omA, a0, a1);
      red[srow][sc] = sq;
    }
    if (h+1 < 8) {
      const float* qp_ = query + ((size_t)b*N_ + n0 + srow)*512 + (h+1)*64 + sc*8;
      pq0 = *(const float4*)qp_; pq1 = *(const float4*)(qp_+4);
    }
    __syncthreads();
    if (lane < 8) {
      int row = w*8 + lane;
      float s = 0.f;
      #pragma unroll
      for (int c = 0; c < 8; ++c) s += red[row][c];
      diag_s[row] = 0.5f*s;
    }
    f32x4 dlo[4], dhi[4];
    #pragma unroll
    for (int ft = 0; ft < 4; ++ft) { dlo[ft] = (f32x4){0,0,0,0}; dhi[ft] = (f32x4){0,0,0,0}; }
    #pragma unroll
    for (int ks = 0; ks < 6; ++ks) {
      short8v alo = *(const short8v*)&kcb[fcol][ks*32 + g*8];
      short8v ahi = *(const short8v*)&kcb[16+fcol][ks*32 + g*8];
      #pragma unroll
      for (int ft = 0; ft < 4; ++ft) {
        dlo[ft] = __builtin_amdgcn_mfma_f32_16x16x32_bf16(alo, pb[ft][ks], dlo[ft], 0, 0, 0);
        dhi[ft] = __builtin_amdgcn_mfma_f32_16x16x32_bf16(ahi, pb[ft][ks], dhi[ft], 0, 0, 0);
      }
    }
    {
      float ml[4], mh[4];
      #pragma unroll
      for (int j = 0; j < 4; ++j) {
        ml[j] = fmaxf(fmaxf(dlo[0][j], dlo[1][j]), fmaxf(dlo[2][j], dlo[3][j]));
        mh[j] = fmaxf(fmaxf(dhi[0][j], dhi[1][j]), fmaxf(dhi[2][j], dhi[3][j]));
      }
      #pragma unroll
      for (int m = 1; m <= 8; m <<= 1) {
        #pragma unroll
        for (int j = 0; j < 4; ++j) {
          ml[j] = fmaxf(ml[j], __shfl_xor(ml[j], m));
          mh[j] = fmaxf(mh[j], __shfl_xor(mh[j], m));
        }
      }
      if (fcol == 0) {
        #pragma unroll
        for (int j = 0; j < 4; ++j) {
          mredw[w][g4+j] = ml[j];
          mredw[w][16+g4+j] = mh[j];
        }
      }
    }
    __syncthreads();
    if (tid < 32)
      mq[tid] = fmaxf(fmaxf(mredw[0][tid], mredw[1][tid]), fmaxf(mredw[2][tid], mredw[3][tid]));
    __syncthreads();
    {
      float dp[8] = {0,0,0,0,0,0,0,0};
      #pragma unroll
      for (int ft = 0; ft < 4; ++ft) {
        int f = w*64 + ft*16 + fcol;
        float kf = ksl[f];
        #pragma unroll
        for (int j = 0; j < 4; ++j) {
          int n = g4 + j;
          float Ex = RATIO * (__expf(dlo[ft][j] - diag_s[n] - mq[n]) + SM_EPS);
          dp[j] += Ex * kf;
          qpE[n][f] = f2bs(Ex);
          int n2 = 16 + g4 + j;
          float Ex2 = RATIO * (__expf(dhi[ft][j] - diag_s[n2] - mq[n2]) + SM_EPS);
          dp[4+j] += Ex2 * kf;
          qpE[n2][f] = f2bs(Ex2);
        }
      }
      #pragma unroll
      for (int m = 1; m <= 8; m <<= 1)
        #pragma unroll
        for (int s = 0; s < 8; ++s) dp[s] += __shfl_xor(dp[s], m);
      if (fcol == 0) {
        #pragma unroll
        for (int j = 0; j < 4; ++j) {
          red2[w][g4+j] = dp[j];
          red2[w][16+g4+j] = dp[4+j];
        }
      }
    }
    __syncthreads();
    if (tid < 32)
      dnm[tid] = 1.f / (red2[0][tid] + red2[1][tid] + red2[2][tid] + red2[3][tid] + NORM_EPS);
    __syncthreads();
    {
      const unsigned short* ct = (const unsigned short*)&W[OFF_CTX + (size_t)bh*16384];
      int e = w*16 + fcol;
      f32x4 pa[2];
      pa[0] = (f32x4){0,0,0,0}; pa[1] = (f32x4){0,0,0,0};
      #pragma unroll
      for (int ks = 0; ks < 8; ++ks) {
        short8v bv = *(const short8v*)&ct[e*256 + ks*32 + g*8];
        short8v a0v = *(const short8v*)&qpE[fcol][ks*32 + g*8];
        short8v a1v = *(const short8v*)&qpE[16+fcol][ks*32 + g*8];
        pa[0] = __builtin_amdgcn_mfma_f32_16x16x32_bf16(a0v, bv, pa[0], 0, 0, 0);
        pa[1] = __builtin_amdgcn_mfma_f32_16x16x32_bf16(a1v, bv, pa[1], 0, 0, 0);
      }
      #pragma unroll
      for (int rt = 0; rt < 2; ++rt)
        #pragma unroll
        for (int j = 0; j < 4; ++j) {
          int n = rt*16 + g4 + j;
          attnb[n][e] = f2bs(pa[rt][j] * dnm[n]);
        }
    }
    __syncthreads();
    {
      #pragma unroll
      for (int ks2 = 0; ks2 < 2; ++ks2) {
        short8v bo = *(const short8v*)&owb[(size_t)(w*16 + fcol)*512 + h*64 + ks2*32 + g*8];
        short8v aa0 = *(const short8v*)&attnb[fcol][ks2*32 + g*8];
        short8v aa1 = *(const short8v*)&attnb[16+fcol][ks2*32 + g*8];
        oacc[0] = __builtin_amdgcn_mfma_f32_16x16x32_bf16(aa0, bo, oacc[0], 0, 0, 0);
        oacc[1] = __builtin_amdgcn_mfma_f32_16x16x32_bf16(aa1, bo, oacc[1], 0, 0, 0);
      }
    }
  }
  {
    float bj = outb[w*16 + fcol];
    #pragma unroll
    for (int rt = 0; rt < 2; ++rt)
      #pragma unroll
      for (int j = 0; j < 4; ++j) {
        int n = n0 + rt*16 + g4 + j;
        out[((size_t)b*N_ + n)*64 + w*16 + fcol] = oacc[rt][j] + bj;
      }
  }
}

extern "C" void kernel_launch(void* const* d_in, const int* in_sizes, int n_in,
                              void* d_out, int out_size, void* d_ws, size_t ws_size,
                              hipStream_t stream) {
  const float* query  = (const float*)d_in[0];
  const float* key    = (const float*)d_in[1];
  const float* value  = (const float*)d_in[2];
  const float* coords = (const float*)d_in[3];
  const void*  mask   = d_in[4];
  const float* wrpe   = (const float*)d_in[5];
  const float* omR    = (const float*)d_in[6];
  const float* omA    = (const float*)d_in[7];
  const float* proj   = (const float*)d_in[8];
  const float* outw   = (const float*)d_in[9];
  const float* outb   = (const float*)d_in[10];
  float* W = (float*)d_ws;
  float* out = (float*)d_out;

  hipMemsetAsync(W + ZERO_BEG, 0, (size_t)(ZERO_END - ZERO_BEG)*sizeof(float), stream);
  hipLaunchKernelGGL(k_consts,   dim3(32),         dim3(256), 0, stream, wrpe, outw,
                     (const unsigned int*)mask, W);
  hipLaunchKernelGGL(k_pass1,    dim3(32*NCH*2),   dim3(256), 0, stream, key, value, coords, mask,
                     omR, omA, proj, W);
  hipLaunchKernelGGL(k_finalize, dim3(32),         dim3(256), 0, stream, W);
  hipLaunchKernelGGL(k_pass2,    dim3(1024),       dim3(256), 0, stream, query, coords, omR, omA,
                     proj, outb, W, out);
}

// Round 21
// 270.111 us; speedup vs baseline: 1.4334x; 1.0077x over previous
//
#include <hip/hip_runtime.h>
#include <hip/hip_bf16.h>
#include <math.h>

constexpr int B_ = 4, N_ = 8192, H_ = 8;
constexpr float SQT    = 0.35355339059327373f;   // sqrt(SOFTMAX_TEMP)
constexpr float RFF_S  = 0.17677669529663687f;   // sqrt(2/64)
constexpr float RATIO  = 0.0625f;                // 256^-0.5
constexpr float SM_EPS = 1e-6f;
constexpr float NORM_EPS = 1e-6f;

constexpr int NCH = 16, CHUNK = N_ / NCH;        // pass1: 512 rows per (bh,ch), grid 32*NCH*2

// ws layout (float offsets)
constexpr int OFF_CONST = 0;
constexpr int OFF_FLAG  = 63;
constexpr int OFF_MK    = 64;
constexpr int OFF_NMASK = 96;
constexpr int OFF_KSUM  = 128;      // 32*256
constexpr int OFF_VSUM  = 8320;     // 32*64
constexpr int OFF_BMAX  = 10368;    // 1024 (32 bh * 16 ch * 2 fh)
constexpr int OFF_CTX   = 11392;    // 32*256*64 f32; finalize converts in-place to bf16 ctxT[bh][64][256]
constexpr int OFF_OWB   = 535680;   // 64*512 bf16 out_w (16384 float-slots)
constexpr int ZERO_BEG  = OFF_NMASK;
constexpr int ZERO_END  = OFF_CTX + 32*16384;

typedef __attribute__((ext_vector_type(8))) short short8v;
typedef __attribute__((ext_vector_type(4))) float f32x4;

__device__ __forceinline__ unsigned short f2bs(float x) {
  __hip_bfloat16 b = __float2bfloat16(x);   // HW cvt (RNE)
  return *reinterpret_cast<unsigned short*>(&b);
}
__device__ __forceinline__ float bs2f(unsigned short s) {
  union { unsigned int u; float f; } v; v.u = ((unsigned int)s) << 16;
  return v.f;
}

__global__ __launch_bounds__(256)
void k_consts(const float* __restrict__ wrpe, const float* __restrict__ outw,
              const unsigned int* __restrict__ maskw, float* __restrict__ W) {
  __shared__ float exs[128];
  __shared__ float qwv[8][2];
  __shared__ int f_gt1, f_oddnz, f_evennz;
  int tid = threadIdx.x;
  int nb = gridDim.x, bid = blockIdx.x;
  for (int i = bid*256 + tid; i < 32*NCH*2; i += nb*256) W[OFF_BMAX + i] = -INFINITY;
  unsigned short* owb = (unsigned short*)&W[OFF_OWB];
  for (int i = bid*256 + tid; i < 64*512; i += nb*256) owb[i] = f2bs(outw[i]);
  if (bid != 0) return;
  if (tid == 0) { f_gt1 = 0; f_oddnz = 0; f_evennz = 0; }
  __syncthreads();
  {
    int gt1 = 0, oddnz = 0, evennz = 0;
    for (int i = tid; i < 8192; i += 256) {
      unsigned int v = maskw[i];
      if (v > 1u) gt1 = 1;
      if (v != 0u) { if (i & 1) oddnz = 1; else evennz = 1; }
    }
    if (gt1)    atomicOr(&f_gt1, 1);
    if (oddnz)  atomicOr(&f_oddnz, 1);
    if (evennz) atomicOr(&f_evennz, 1);
  }
  if (tid < 128) {
    int h = tid >> 4, r = (tid >> 3) & 1, c = (tid >> 2) & 1, k = tid & 3;
    float s = 0.f;
    for (int d = 0; d < 64; ++d) s += wrpe[(h*64 + d)*16 + r*8 + c*4 + k];
    exs[tid] = expf(fminf(s, 50.f));
  }
  __syncthreads();
  if (tid == 0) {
    float flag = 0.f;
    if (f_gt1) flag = 1.f;
    else if (!f_oddnz && f_evennz) flag = 2.f;
    W[OFF_FLAG] = flag;
  }
  if (tid < 32) {
    int h = tid >> 2, r = (tid >> 1) & 1, c = tid & 1;
    float s = 0.f;
    for (int k = 0; k < 4; ++k) s += exs[h*16 + r*8 + c*4 + k];
    if (c == 0) W[OFF_CONST + h*8 + 3 + r] = sqrtf(s);
    else        qwv[h][r] = s;
  }
  __syncthreads();
  if (tid < 8) {
    int h = tid;
    float s0 = sqrtf(qwv[h][0]), s1 = sqrtf(qwv[h][1]);
    W[OFF_CONST + h*8 + 0] = s0;
    W[OFF_CONST + h*8 + 1] = s0;
    W[OFF_CONST + h*8 + 2] = s1;
  }
}

__device__ __forceinline__ int read_mask(const void* maskp, int mtype, size_t idx) {
  if (mtype == 1) return (int)((const unsigned char*)maskp)[idx];
  if (mtype == 2) return (int)((const long long*)maskp)[idx];
  return ((const int*)maskp)[idx];
}

// RFF: compute 8 features for this thread's sc block, return sumsq; vectorized b128 stores.
__device__ __forceinline__ float rff_store(unsigned short kcbrow[200], int sc,
                                           float px, float py, float pz,
                                           const float* omR, const float* omA,
                                           float a0, float a1) {
  float sq = 0.f;
  short8v cv8, sv8;
  if (sc < 4) {
    #pragma unroll
    for (int ii = 0; ii < 8; ++ii) {
      int idx = sc*8 + ii;
      float u = px*omR[idx] + py*omR[32+idx];
      float sn, cs; __sincosf(u, &sn, &cs);
      float cv = cs*a0, sv = sn*a0;
      cv8[ii] = f2bs(cv); sv8[ii] = f2bs(sv);
      sq += cv*cv + sv*sv;
    }
    *(short8v*)&kcbrow[64 + sc*8] = cv8;
    *(short8v*)&kcbrow[96 + sc*8] = sv8;
  } else {
    #pragma unroll
    for (int ii = 0; ii < 8; ++ii) {
      int j = (sc-4)*8 + ii;
      float u = pz*omA[j];
      float sn, cs; __sincosf(u, &sn, &cs);
      float cv = cs*a1, sv = sn*a1;
      cv8[ii] = f2bs(cv); sv8[ii] = f2bs(sv);
      sq += cv*cv + sv*sv;
    }
    *(short8v*)&kcbrow[128 + (sc-4)*8] = cv8;
    *(short8v*)&kcbrow[160 + (sc-4)*8] = sv8;
  }
  return sq;
}

// 256 threads; block = (bh, ch, fhalf): 128 features each.
__global__ __launch_bounds__(256, 2)
void k_pass1(const float* __restrict__ key, const float* __restrict__ value,
             const float* __restrict__ coords, const void* __restrict__ maskp,
             const float* __restrict__ omR_g, const float* __restrict__ omA_g,
             const float* __restrict__ proj, float* __restrict__ W) {
  int bh = blockIdx.x / (NCH*2);
  int rem = blockIdx.x % (NCH*2);
  int ch = rem >> 1, fh = rem & 1;
  int b = bh >> 3, h = bh & 7;
  int f_base = fh*128;
  int tid = threadIdx.x;
  int w = tid >> 6, lane = tid & 63, g = lane >> 4, fcol = lane & 15, g4 = g*4;

  __shared__ __align__(16) unsigned short kcb[32][200];
  __shared__ __align__(16) unsigned short vtT[64][40];   // [e][swizzled n]
  __shared__ __align__(16) unsigned short eT[128][40];
  __shared__ float red[256];
  __shared__ float diag_s[32];
  __shared__ float mtile_s[32];
  __shared__ float wred[4];
  __shared__ float omR[64], omA[32];

  if (tid < 64) omR[tid] = omR_g[tid];
  if (tid < 32) omA[tid] = omA_g[tid];
  int mtype = (int)W[OFF_FLAG];
  float s0 = W[OFF_CONST + h*8 + 0];
  float s1 = W[OFF_CONST + h*8 + 1];
  float s2 = W[OFF_CONST + h*8 + 2];
  float a0 = W[OFF_CONST + h*8 + 3] * RFF_S;
  float a1 = W[OFF_CONST + h*8 + 4] * RFF_S;

  short8v pb[2][6];
  #pragma unroll
  for (int ft = 0; ft < 2; ++ft) {
    int f = f_base + w*32 + ft*16 + fcol;
    #pragma unroll
    for (int ks = 0; ks < 6; ++ks) {
      const float* p = proj + (size_t)f*192 + ks*32 + g*8;
      float4 p0 = *(const float4*)p;
      float4 p1 = *(const float4*)(p + 4);
      short8v v;
      v[0]=f2bs(p0.x); v[1]=f2bs(p0.y); v[2]=f2bs(p0.z); v[3]=f2bs(p0.w);
      v[4]=f2bs(p1.x); v[5]=f2bs(p1.y); v[6]=f2bs(p1.z); v[7]=f2bs(p1.w);
      pb[ft][ks] = v;
    }
  }

  f32x4 ctxa[2][4];
  #pragma unroll
  for (int i = 0; i < 2; ++i)
    #pragma unroll
    for (int j = 0; j < 4; ++j) ctxa[i][j] = (f32x4){0.f,0.f,0.f,0.f};
  float ksum_p[2] = {0.f,0.f};
  float vs8[8] = {0.f,0.f,0.f,0.f,0.f,0.f,0.f,0.f};
  float maxd = -INFINITY, nm = 0.f;

  int srow = tid >> 3, sc = tid & 7;
  int wgrp = srow >> 3;

  // ---- prefetch tile 0 ----
  float4 pk0, pk1, pv0, pv1;
  float pcx, pcy, pcz, pmv;
  {
    size_t nidx = (size_t)b*N_ + ch*CHUNK + srow;
    const float* kp = key + nidx*512 + h*64 + sc*8;
    const float* vp = value + nidx*512 + h*64 + sc*8;
    pk0 = *(const float4*)kp; pk1 = *(const float4*)(kp+4);
    pv0 = *(const float4*)vp; pv1 = *(const float4*)(vp+4);
    const float* cp = coords + nidx*3;
    pcx = cp[0]; pcy = cp[1]; pcz = cp[2];
    pmv = (read_mask(maskp, mtype, nidx) != 0) ? 1.f : 0.f;
  }

  for (int t = 0; t < CHUNK/32; ++t) {
    __syncthreads();
    {
      float kk[8] = {pk0.x*SQT,pk0.y*SQT,pk0.z*SQT,pk0.w*SQT,pk1.x*SQT,pk1.y*SQT,pk1.z*SQT,pk1.w*SQT};
      float sq = 0.f;
      short8v kv;
      #pragma unroll
      for (int i = 0; i < 8; ++i) { sq += kk[i]*kk[i]; kv[i] = f2bs(kk[i]); }
      *(short8v*)&kcb[srow][sc*8] = kv;
      float vv[8] = {pv0.x,pv0.y,pv0.z,pv0.w,pv1.x,pv1.y,pv1.z,pv1.w};
      {
        int col = ((wgrp ^ (sc & 3)) << 3) | (srow & 7);
        #pragma unroll
        for (int i = 0; i < 8; ++i) vtT[sc*8 + i][col] = f2bs(vv[i]);
      }
      if (fh == 0 && pmv != 0.f) {
        #pragma unroll
        for (int i = 0; i < 8; ++i) vs8[i] += vv[i];
      }
      sq += rff_store(kcb[srow], sc, pcx*s0, pcy*s1, pcz*s2, omR, omA, a0, a1);
      red[tid] = sq;
      if (sc == 0) mtile_s[srow] = pmv;
    }
    if (t+1 < CHUNK/32) {
      size_t nidx = (size_t)b*N_ + ch*CHUNK + (t+1)*32 + srow;
      const float* kp = key + nidx*512 + h*64 + sc*8;
      const float* vp = value + nidx*512 + h*64 + sc*8;
      pk0 = *(const float4*)kp; pk1 = *(const float4*)(kp+4);
      pv0 = *(const float4*)vp; pv1 = *(const float4*)(vp+4);
      const float* cp = coords + nidx*3;
      pcx = cp[0]; pcy = cp[1]; pcz = cp[2];
      pmv = (read_mask(maskp, mtype, nidx) != 0) ? 1.f : 0.f;
    }
    __syncthreads();
    if (tid < 32) {
      float s = 0.f;
      #pragma unroll
      for (int c = 0; c < 8; ++c) s += red[tid*8 + c];
      diag_s[tid] = 0.5f*s;
    }
    f32x4 d[2][2];
    #pragma unroll
    for (int hh = 0; hh < 2; ++hh)
      #pragma unroll
      for (int ft = 0; ft < 2; ++ft) d[hh][ft] = (f32x4){0,0,0,0};
    #pragma unroll
    for (int ks = 0; ks < 6; ++ks) {
      short8v alo = *(const short8v*)&kcb[fcol][ks*32 + g*8];
      short8v ahi = *(const short8v*)&kcb[16 + fcol][ks*32 + g*8];
      #pragma unroll
      for (int ft = 0; ft < 2; ++ft) {
        d[0][ft] = __builtin_amdgcn_mfma_f32_16x16x32_bf16(alo, pb[ft][ks], d[0][ft], 0, 0, 0);
        d[1][ft] = __builtin_amdgcn_mfma_f32_16x16x32_bf16(ahi, pb[ft][ks], d[1][ft], 0, 0, 0);
      }
    }
    __syncthreads();
    if (tid < 32) nm += mtile_s[tid];
    #pragma unroll
    for (int ft = 0; ft < 2; ++ft) {
      int fl = w*32 + ft*16 + fcol;
      #pragma unroll
      for (int hh = 0; hh < 2; ++hh) {
        unsigned short us[4];
        #pragma unroll
        for (int j = 0; j < 4; ++j) {
          int n = hh*16 + g4 + j;
          float x = d[hh][ft][j];
          maxd = fmaxf(maxd, x);
          float E = (mtile_s[n] != 0.f) ? __expf(x - diag_s[n]) : 0.f;
          ksum_p[ft] += E;
          us[j] = f2bs(E);
        }
        *(unsigned int*)&eT[fl][hh*16 + g4]     = (unsigned int)us[0] | ((unsigned int)us[1] << 16);
        *(unsigned int*)&eT[fl][hh*16 + g4 + 2] = (unsigned int)us[2] | ((unsigned int)us[3] << 16);
      }
    }
    __syncthreads();
    {
      short8v av[2];
      #pragma unroll
      for (int ft = 0; ft < 2; ++ft)
        av[ft] = *(const short8v*)&eT[w*32 + ft*16 + fcol][g*8];
      #pragma unroll
      for (int et = 0; et < 4; ++et) {
        int e = et*16 + fcol;
        int gr = g ^ ((e >> 3) & 3);
        short8v bv = *(const short8v*)&vtT[e][gr*8];
        #pragma unroll
        for (int ft = 0; ft < 2; ++ft)
          ctxa[ft][et] = __builtin_amdgcn_mfma_f32_16x16x32_bf16(av[ft], bv, ctxa[ft][et], 0, 0, 0);
      }
    }
  }

  #pragma unroll
  for (int ft = 0; ft < 2; ++ft) {
    float k0 = ksum_p[ft];
    k0 += __shfl_xor(k0, 16);
    k0 += __shfl_xor(k0, 32);
    if (g == 0)
      atomicAdd(&W[OFF_KSUM + bh*256 + f_base + w*32 + ft*16 + fcol], k0);
  }
  #pragma unroll
  for (int ft = 0; ft < 2; ++ft)
    #pragma unroll
    for (int et = 0; et < 4; ++et)
      #pragma unroll
      for (int j = 0; j < 4; ++j) {
        int f = f_base + w*32 + ft*16 + g4 + j;
        int e = et*16 + fcol;
        atomicAdd(&W[OFF_CTX + (size_t)bh*16384 + f*64 + e], ctxa[ft][et][j]);
      }
  if (fh == 0) {
    #pragma unroll
    for (int m = 8; m <= 32; m <<= 1)
      #pragma unroll
      for (int i = 0; i < 8; ++i) vs8[i] += __shfl_xor(vs8[i], m);
    __syncthreads();
    if (lane < 8) {
      #pragma unroll
      for (int i = 0; i < 8; ++i) red[w*64 + lane*8 + i] = vs8[i];
    }
    __syncthreads();
    if (tid < 64) {
      float s = red[tid] + red[64+tid] + red[128+tid] + red[192+tid];
      atomicAdd(&W[OFF_VSUM + bh*64 + tid], s);
    }
    if (tid < 32) {
      float nn = nm;
      nn += __shfl_xor(nn, 1); nn += __shfl_xor(nn, 2);
      nn += __shfl_xor(nn, 4); nn += __shfl_xor(nn, 8);
      nn += __shfl_xor(nn, 16);
      if (tid == 0) atomicAdd(&W[OFF_NMASK + bh], nn);
    }
  }
  #pragma unroll
  for (int m = 1; m <= 32; m <<= 1) maxd = fmaxf(maxd, __shfl_xor(maxd, m));
  if (lane == 0) wred[w] = maxd;
  __syncthreads();
  if (tid == 0) {
    float m = fmaxf(fmaxf(wred[0], wred[1]), fmaxf(wred[2], wred[3]));
    W[OFF_BMAX + blockIdx.x] = m;
  }
}

// finalize: per-bh global max, scale ksum/ctx, convert ctx to bf16 ctxT
__global__ __launch_bounds__(256)
void k_finalize(float* __restrict__ W) {
  __shared__ float buf[16384];
  __shared__ float mk_s;
  int bh = blockIdx.x;
  int tid = threadIdx.x;
  if (tid < 32) {
    float m = W[OFF_BMAX + bh*(NCH*2) + tid];
    #pragma unroll
    for (int s = 1; s < 32; s <<= 1) m = fmaxf(m, __shfl_xor(m, s));
    if (tid == 0) { mk_s = m; W[OFF_MK + bh] = m; }
  }
  __syncthreads();
  float emk  = RATIO * __expf(-mk_s);
  float epsr = RATIO * SM_EPS;
  float nm = W[OFF_NMASK + bh];
  W[OFF_KSUM + bh*256 + tid] = emk*W[OFF_KSUM + bh*256 + tid] + epsr*nm;
  float* ctx = &W[OFF_CTX + (size_t)bh*16384];
  const float* vsum = &W[OFF_VSUM + bh*64];
  for (int i = tid; i < 16384; i += 256) {
    int e = i & 63;
    buf[i] = emk*ctx[i] + epsr*vsum[e];
  }
  __syncthreads();
  unsigned short* ct = (unsigned short*)ctx;
  for (int i = tid; i < 16384; i += 256) {
    int e = i >> 8, f = i & 255;
    ct[i] = f2bs(buf[f*64 + e]);
  }
}

__global__ __launch_bounds__(256, 2)
void k_pass2(const float* __restrict__ query, const float* __restrict__ coords,
             const float* __restrict__ omR_g, const float* __restrict__ omA_g,
             const float* __restrict__ proj, const float* __restrict__ outb,
             float* __restrict__ W, float* __restrict__ out) {
  int b  = blockIdx.x >> 8;
  int n0 = (blockIdx.x & 255) * 32;
  int tid = threadIdx.x;
  int w = tid >> 6, lane = tid & 63, g = lane >> 4, fcol = lane & 15, g4 = g*4;

  __shared__ __align__(16) unsigned short kcb[32][200];
  __shared__ __align__(16) unsigned short qpE[32][280];
  __shared__ __align__(16) unsigned short attnb[32][72];
  __shared__ float red[32][8];
  __shared__ float diag_s[32];
  __shared__ float mredw[4][32];
  __shared__ float red2[4][32];
  __shared__ float mq[32];
  __shared__ float dnm[32];
  __shared__ float ksl[256];
  __shared__ float omR[64], omA[32];

  if (tid < 64) omR[tid] = omR_g[tid];
  if (tid < 32) omA[tid] = omA_g[tid];

  short8v pb[4][6];
  #pragma unroll
  for (int ft = 0; ft < 4; ++ft) {
    int f = w*64 + ft*16 + fcol;
    #pragma unroll
    for (int ks = 0; ks < 6; ++ks) {
      const float* p = proj + (size_t)f*192 + ks*32 + g*8;
      float4 p0 = *(const float4*)p;
      float4 p1 = *(const float4*)(p + 4);
      short8v v;
      v[0]=f2bs(p0.x); v[1]=f2bs(p0.y); v[2]=f2bs(p0.z); v[3]=f2bs(p0.w);
      v[4]=f2bs(p1.x); v[5]=f2bs(p1.y); v[6]=f2bs(p1.z); v[7]=f2bs(p1.w);
      pb[ft][ks] = v;
    }
  }

  const unsigned short* owb = (const unsigned short*)&W[OFF_OWB];
  int srow = tid >> 3, sc = tid & 7;
  f32x4 oacc[2];
  oacc[0] = (f32x4){0,0,0,0}; oacc[1] = (f32x4){0,0,0,0};

  float cx, cy, cz;
  float4 pq0, pq1;
  {
    size_t nidx = (size_t)b*N_ + n0 + srow;
    const float* cp = coords + nidx*3;
    cx = cp[0]; cy = cp[1]; cz = cp[2];
    const float* qp_ = query + nidx*512 + sc*8;
    pq0 = *(const float4*)qp_; pq1 = *(const float4*)(qp_+4);
  }

  // prefetch ctxT B-fragments for h=0 (L2-resident; hides ~200cyc L2 latency)
  short8v bvp[8];
  {
    const unsigned short* ct0 = (const unsigned short*)&W[OFF_CTX + (size_t)(b*8)*16384];
    int e = w*16 + fcol;
    #pragma unroll
    for (int ks = 0; ks < 8; ++ks)
      bvp[ks] = *(const short8v*)&ct0[e*256 + ks*32 + g*8];
  }

  for (int h = 0; h < 8; ++h) {
    int bh = b*8 + h;
    float s0 = W[OFF_CONST + h*8 + 0];
    float s1 = W[OFF_CONST + h*8 + 1];
    float s2 = W[OFF_CONST + h*8 + 2];
    float a0 = W[OFF_CONST + h*8 + 3] * RFF_S;
    float a1 = W[OFF_CONST + h*8 + 4] * RFF_S;
    __syncthreads();
    ksl[tid] = W[OFF_KSUM + bh*256 + tid];
    {
      float kk[8] = {pq0.x*SQT,pq0.y*SQT,pq0.z*SQT,pq0.w*SQT,pq1.x*SQT,pq1.y*SQT,pq1.z*SQT,pq1.w*SQT};
      float sq = 0.f;
      short8v kv;
      #pragma unroll
      for (int i = 0; i < 8; ++i) { sq += kk[i]*kk[i]; kv[i] = f2bs(kk[i]); }
      *(short8v*)&kcb[srow][sc*8] = kv;
      sq += rff_store(kcb[srow], sc, cx*s0, cy*s1, cz*s2, omR, omA, a0, a1);
      red[srow][sc] = sq;
    }
    if (h+1 < 8) {
      const float* qp_ = query + ((size_t)b*N_ + n0 + srow)*512 + (h+1)*64 + sc*8;
      pq0 = *(const float4*)qp_; pq1 = *(const float4*)(qp_+4);
    }
    __syncthreads();
    if (lane < 8) {
      int row = w*8 + lane;
      float s = 0.f;
      #pragma unroll
      for (int c = 0; c < 8; ++c) s += red[row][c];
      diag_s[row] = 0.5f*s;
    }
    f32x4 dlo[4], dhi[4];
    #pragma unroll
    for (int ft = 0; ft < 4; ++ft) { dlo[ft] = (f32x4){0,0,0,0}; dhi[ft] = (f32x4){0,0,0,0}; }
    #pragma unroll
    for (int ks = 0; ks < 6; ++ks) {
      short8v alo = *(const short8v*)&kcb[fcol][ks*32 + g*8];
      short8v ahi = *(const short8v*)&kcb[16+fcol][ks*32 + g*8];
      #pragma unroll
      for (int ft = 0; ft < 4; ++ft) {
        dlo[ft] = __builtin_amdgcn_mfma_f32_16x16x32_bf16(alo, pb[ft][ks], dlo[ft], 0, 0, 0);
        dhi[ft] = __builtin_amdgcn_mfma_f32_16x16x32_bf16(ahi, pb[ft][ks], dhi[ft], 0, 0, 0);
      }
    }
    {
      float ml[4], mh[4];
      #pragma unroll
      for (int j = 0; j < 4; ++j) {
        ml[j] = fmaxf(fmaxf(dlo[0][j], dlo[1][j]), fmaxf(dlo[2][j], dlo[3][j]));
        mh[j] = fmaxf(fmaxf(dhi[0][j], dhi[1][j]), fmaxf(dhi[2][j], dhi[3][j]));
      }
      #pragma unroll
      for (int m = 1; m <= 8; m <<= 1) {
        #pragma unroll
        for (int j = 0; j < 4; ++j) {
          ml[j] = fmaxf(ml[j], __shfl_xor(ml[j], m));
          mh[j] = fmaxf(mh[j], __shfl_xor(mh[j], m));
        }
      }
      if (fcol == 0) {
        #pragma unroll
        for (int j = 0; j < 4; ++j) {
          mredw[w][g4+j] = ml[j];
          mredw[w][16+g4+j] = mh[j];
        }
      }
    }
    __syncthreads();
    if (tid < 32)
      mq[tid] = fmaxf(fmaxf(mredw[0][tid], mredw[1][tid]), fmaxf(mredw[2][tid], mredw[3][tid]));
    __syncthreads();
    {
      float dp[8] = {0,0,0,0,0,0,0,0};
      #pragma unroll
      for (int ft = 0; ft < 4; ++ft) {
        int f = w*64 + ft*16 + fcol;
        float kf = ksl[f];
        #pragma unroll
        for (int j = 0; j < 4; ++j) {
          int n = g4 + j;
          float Ex = RATIO * (__expf(dlo[ft][j] - diag_s[n] - mq[n]) + SM_EPS);
          dp[j] += Ex * kf;
          qpE[n][f] = f2bs(Ex);
          int n2 = 16 + g4 + j;
          float Ex2 = RATIO * (__expf(dhi[ft][j] - diag_s[n2] - mq[n2]) + SM_EPS);
          dp[4+j] += Ex2 * kf;
          qpE[n2][f] = f2bs(Ex2);
        }
      }
      #pragma unroll
      for (int m = 1; m <= 8; m <<= 1)
        #pragma unroll
        for (int s = 0; s < 8; ++s) dp[s] += __shfl_xor(dp[s], m);
      if (fcol == 0) {
        #pragma unroll
        for (int j = 0; j < 4; ++j) {
          red2[w][g4+j] = dp[j];
          red2[w][16+g4+j] = dp[4+j];
        }
      }
    }
    __syncthreads();
    if (tid < 32)
      dnm[tid] = 1.f / (red2[0][tid] + red2[1][tid] + red2[2][tid] + red2[3][tid] + NORM_EPS);
    __syncthreads();
    {
      int e = w*16 + fcol;
      f32x4 pa[2];
      pa[0] = (f32x4){0,0,0,0}; pa[1] = (f32x4){0,0,0,0};
      #pragma unroll
      for (int ks = 0; ks < 8; ++ks) {
        short8v a0v = *(const short8v*)&qpE[fcol][ks*32 + g*8];
        short8v a1v = *(const short8v*)&qpE[16+fcol][ks*32 + g*8];
        pa[0] = __builtin_amdgcn_mfma_f32_16x16x32_bf16(a0v, bvp[ks], pa[0], 0, 0, 0);
        pa[1] = __builtin_amdgcn_mfma_f32_16x16x32_bf16(a1v, bvp[ks], pa[1], 0, 0, 0);
      }
      // prefetch next head's ctxT fragments (consumed 3 barrier-phases later)
      if (h+1 < 8) {
        const unsigned short* ctn = (const unsigned short*)&W[OFF_CTX + (size_t)(bh+1)*16384];
        #pragma unroll
        for (int ks = 0; ks < 8; ++ks)
          bvp[ks] = *(const short8v*)&ctn[e*256 + ks*32 + g*8];
      }
      #pragma unroll
      for (int rt = 0; rt < 2; ++rt)
        #pragma unroll
        for (int j = 0; j < 4; ++j) {
          int n = rt*16 + g4 + j;
          attnb[n][e] = f2bs(pa[rt][j] * dnm[n]);
        }
    }
    __syncthreads();
    {
      #pragma unroll
      for (int ks2 = 0; ks2 < 2; ++ks2) {
        short8v bo = *(const short8v*)&owb[(size_t)(w*16 + fcol)*512 + h*64 + ks2*32 + g*8];
        short8v aa0 = *(const short8v*)&attnb[fcol][ks2*32 + g*8];
        short8v aa1 = *(const short8v*)&attnb[16+fcol][ks2*32 + g*8];
        oacc[0] = __builtin_amdgcn_mfma_f32_16x16x32_bf16(aa0, bo, oacc[0], 0, 0, 0);
        oacc[1] = __builtin_amdgcn_mfma_f32_16x16x32_bf16(aa1, bo, oacc[1], 0, 0, 0);
      }
    }
  }
  {
    float bj = outb[w*16 + fcol];
    #pragma unroll
    for (int rt = 0; rt < 2; ++rt)
      #pragma unroll
      for (int j = 0; j < 4; ++j) {
        int n = n0 + rt*16 + g4 + j;
        out[((size_t)b*N_ + n)*64 + w*16 + fcol] = oacc[rt][j] + bj;
      }
  }
}

extern "C" void kernel_launch(void* const* d_in, const int* in_sizes, int n_in,
                              void* d_out, int out_size, void* d_ws, size_t ws_size,
                              hipStream_t stream) {
  const float* query  = (const float*)d_in[0];
  const float* key    = (const float*)d_in[1];
  const float* value  = (const float*)d_in[2];
  const float* coords = (const float*)d_in[3];
  const void*  mask   = d_in[4];
  const float* wrpe   = (const float*)d_in[5];
  const float* omR    = (const float*)d_in[6];
  const float* omA    = (const float*)d_in[7];
  const float* proj   = (const float*)d_in[8];
  const float* outw   = (const float*)d_in[9];
  const float* outb   = (const float*)d_in[10];
  float* W = (float*)d_ws;
  float* out = (float*)d_out;

  hipMemsetAsync(W + ZERO_BEG, 0, (size_t)(ZERO_END - ZERO_BEG)*sizeof(float), stream);
  hipLaunchKernelGGL(k_consts,   dim3(32),         dim3(256), 0, stream, wrpe, outw,
                     (const unsigned int*)mask, W);
  hipLaunchKernelGGL(k_pass1,    dim3(32*NCH*2),   dim3(256), 0, stream, key, value, coords, mask,
                     omR, omA, proj, W);
  hipLaunchKernelGGL(k_finalize, dim3(32),         dim3(256), 0, stream, W);
  hipLaunchKernelGGL(k_pass2,    dim3(1024),       dim3(256), 0, stream, query, coords, omR, omA,
                     proj, outb, W, out);
}